// Round 1
// 790.424 us; speedup vs baseline: 1.0761x; 1.0761x over previous
//
#include <hip/hip_runtime.h>

#define DEVINL static __device__ __forceinline__
// Same-wave LDS ordering: compiler reorder fence only (validated r10/r12).
#define CFENCE() asm volatile("" ::: "memory")

typedef float v2f __attribute__((ext_vector_type(2)));

DEVINL v2f mk2(float a, float b) { v2f r; r.x = a; r.y = b; return r; }
DEVINL v2f pkfma(v2f a, v2f b, v2f c) { return __builtin_elementwise_fma(a, b, c); }

constexpr float KE = 2.885390081777927f;   // 2*log2(e)

#if __has_builtin(__builtin_amdgcn_exp2f)
DEVINL float exp2_fast(float x) { return __builtin_amdgcn_exp2f(x); }
#else
DEVINL float exp2_fast(float x) { return __expf(x * 0.6931471805599453f); }
#endif

// tanh(x) with t = x*2*log2(e) pre-folded into weights: 1 - 2/(2^t+1).
DEVINL float tanh_pre(float t) {
  float e = exp2_fast(t);
  return 1.0f - 2.0f * __builtin_amdgcn_rcpf(e + 1.0f);
}

template <int CTRL>
DEVINL float dpp_add(float v) {
  int t = __builtin_amdgcn_update_dpp(0, __float_as_int(v), CTRL, 0xF, 0xF, true);
  return v + __int_as_float(t);
}
// All-DPP half-wave totals: lane31 = sum(lanes 0..31), lane63 = sum(32..63).
DEVINL float halves_total(float v) {
  v = dpp_add<0xB1>(v);    // quad_perm [1,0,3,2]
  v = dpp_add<0x4E>(v);    // quad_perm [2,3,0,1]
  v = dpp_add<0x141>(v);   // row_half_mirror
  v = dpp_add<0x140>(v);   // row_mirror
  v = dpp_add<0x142>(v);   // row_bcast15 -> lanes 31,63 hold half totals
  return v;
}
DEVINL float rlane(float v, int l) {
  return __int_as_float(__builtin_amdgcn_readlane(__float_as_int(v), l));
}

// 32-wide dot vs an LDS row (uniform address per half), packed fp32.
DEVINL float dot32(const float* hrow, const v2f* W, float bias) {
  const float4* hp = (const float4*)hrow;
  v2f a0 = mk2(bias, 0.f), a1 = mk2(0.f, 0.f);
  v2f a2 = mk2(0.f, 0.f), a3 = mk2(0.f, 0.f);
#pragma unroll
  for (int q = 0; q < 8; q += 2) {
    float4 x = hp[q], y = hp[q + 1];
    a0 = pkfma(mk2(x.x, x.y), W[2 * q + 0], a0);
    a1 = pkfma(mk2(x.z, x.w), W[2 * q + 1], a1);
    a2 = pkfma(mk2(y.x, y.y), W[2 * q + 2], a2);
    a3 = pkfma(mk2(y.z, y.w), W[2 * q + 3], a3);
  }
  v2f s = (a0 + a1) + (a2 + a3);
  return s.x + s.y;
}
// 16-wide partial dot (k-split r3 layer 1), packed fp32.
DEVINL float pdot16(const float* hrow, const v2f* W) {
  const float4* hp = (const float4*)hrow;
  v2f a0 = mk2(0.f, 0.f), a1 = mk2(0.f, 0.f);
  float4 x = hp[0], y = hp[1];
  a0 = pkfma(mk2(x.x, x.y), W[0], a0);
  a1 = pkfma(mk2(x.z, x.w), W[1], a1);
  a0 = pkfma(mk2(y.x, y.y), W[2], a0);
  a1 = pkfma(mk2(y.z, y.w), W[3], a1);
  x = hp[2]; y = hp[3];
  a0 = pkfma(mk2(x.x, x.y), W[4], a0);
  a1 = pkfma(mk2(x.z, x.w), W[5], a1);
  a0 = pkfma(mk2(y.x, y.y), W[6], a0);
  a1 = pkfma(mk2(y.z, y.w), W[7], a1);
  v2f s = a0 + a1;
  return s.x + s.y;
}

constexpr int TT = 256;

// wave = 1 batch element; lanes 0-31 = net r1 duties, lanes 32-63 = net r2.
// grid 4096 -> 16 waves/CU = 4 waves/EU.
// Software-pipelined: r3's z-eval (and rc1) for step t+1 is computed during
// step t's stages; z4-eval is completed from carried accumulators with one
// pkfma once x_t is live. Fat fence regions hold 2-3 independent chains.
__global__ __attribute__((amdgpu_flat_work_group_size(64, 64)))
__attribute__((amdgpu_waves_per_eu(4, 4))) void reac_kernel(
    const float* __restrict__ useq,   // [B][T] f32
    const float* __restrict__ xz0,    // [B][26] f32
    const float* __restrict__ r1W0, const float* __restrict__ r1b0,
    const float* __restrict__ r1W1, const float* __restrict__ r1b1,
    const float* __restrict__ r1W2, const float* __restrict__ r1b2,
    const float* __restrict__ r2W0, const float* __restrict__ r2b0,
    const float* __restrict__ r2W1, const float* __restrict__ r2b1,
    const float* __restrict__ r2W2, const float* __restrict__ r2b2,
    const float* __restrict__ r3W0, const float* __restrict__ r3b0,
    const float* __restrict__ r3W1, const float* __restrict__ r3b1,
    const float* __restrict__ r3W2, const float* __restrict__ r3b2,
    float2* __restrict__ out)         // [B][T] -> (x0,x1) f32
{
  const int lane = threadIdx.x;
  const int j = lane & 31;
  const bool hi = lane >= 32;      // high half = r2 net / z4 duties
  const int b = blockIdx.x;
  const int xaddr = ((lane ^ 32) << 2);   // ds_bpermute partner address

  // Phase-stagger co-resident blocks (decorrelate LDS-latency stalls).
  {
    int phase = (b >> 8) & 3;
    if (phase & 1) __builtin_amdgcn_s_sleep(2);
    if (phase & 2) __builtin_amdgcn_s_sleep(4);
  }

  auto xchg = [&](float v) -> float {
    return __int_as_float(__builtin_amdgcn_ds_bpermute(xaddr, __float_as_int(v)));
  };

  // ---- per-half net weights (column j), tanh prescale KE folded in ----
  const float* W0p = hi ? r2W0 : r1W0;
  const float* B0p = hi ? r2b0 : r1b0;
  const float* W1p = hi ? r2W1 : r1W1;
  const float* B1p = hi ? r2b1 : r1b1;
  const float* W2p = hi ? r2W2 : r1W2;
  const float sc = hi ? 0.2f : 0.3f;
  float w0K = W0p[j] * KE, b0K = B0p[j] * KE;
  float b1K = B1p[j] * KE;
  float w2sc = W2p[j] * sc;

  v2f W1v[16];
#pragma unroll
  for (int k = 0; k < 16; ++k)
    W1v[k] = mk2(W1p[(2 * k) * 32 + j] * KE, W1p[(2 * k + 1) * 32 + j] * KE);

  // r3 layer-0 weights, per-half arrangement over the 12 aligned z-pairs:
  //   low  (A(z)):      pair m -> rows (2m, 2m+1)
  //   high (A(z4) pre): pair 0 unused (0); pairs 1..7 -> rows (2m-2, 2m-1)
  //                     (the shifted x-history); pairs 8..11 (upseq) as low.
  //   x-pair rows (14,15) deferred to WXv, applied once x is live.
  v2f W0Cv[12];
#pragma unroll
  for (int m = 0; m < 12; ++m) {
    int r = (hi && m >= 1 && m <= 7) ? (2 * m - 2) : (2 * m);
    v2f w = mk2(r3W0[r * 32 + j] * KE, r3W0[(r + 1) * 32 + j] * KE);
    if (hi && m == 0) w = mk2(0.f, 0.f);
    W0Cv[m] = w;
  }
  const v2f WXv = mk2(r3W0[14 * 32 + j] * KE, r3W0[15 * 32 + j] * KE);

  const int kbase = hi ? 16 : 0;
  v2f W1Cv[8];
#pragma unroll
  for (int k = 0; k < 8; ++k)
    W1Cv[k] = mk2(r3W1[(kbase + 2 * k) * 32 + j] * KE,
                  r3W1[(kbase + 2 * k + 1) * 32 + j] * KE);
  float b0CK = r3b0[j] * KE, b1CK = r3b1[j] * KE;
  float w2C02 = r3W2[j] * 0.2f;

  // wave-uniform scalars (biases folded with output scales)
  const float b2sA = r1b2[0] * 0.3f;
  const float b2sB = r2b2[0] * 0.2f;
  const float b2Cs = r3b2[0] * 0.2f - 0.05f;   // folds -F/V*0.5 of dCb

  __shared__ __align__(16) float zs[24];      // z state
  __shared__ __align__(16) float h12[2][32];  // [net][neuron] broadcast
  __shared__ __align__(16) float hR3[3][32];  // [eval: z,z23,z4][neuron]

  float x0 = xz0[b * 26 + 0];
  float x1 = xz0[b * 26 + 1];
  if (!hi && j < 24) zs[j] = xz0[b * 26 + 2 + j];
  CFENCE();

  // r3 layer-0 over current zs: low -> A(z) accs, high -> A(z4)-prefix accs.
  auto r3_l0 = [&](v2f& aaO, v2f& abO) {
    const float4* zp4 = (const float4*)&zs[0];
    float4 z0v = zp4[0], z1v = zp4[1], z2v = zp4[2], z3v = zp4[3];
    float4 u0v = zp4[4], u1v = zp4[5];
    v2f aa = mk2(b0CK, 0.f), ab = mk2(0.f, 0.f);
    aa = pkfma(mk2(z0v.x, z0v.y), W0Cv[0], aa);
    ab = pkfma(mk2(z0v.z, z0v.w), W0Cv[1], ab);
    aa = pkfma(mk2(z1v.x, z1v.y), W0Cv[2], aa);
    ab = pkfma(mk2(z1v.z, z1v.w), W0Cv[3], ab);
    aa = pkfma(mk2(z2v.x, z2v.y), W0Cv[4], aa);
    ab = pkfma(mk2(z2v.z, z2v.w), W0Cv[5], ab);
    aa = pkfma(mk2(z3v.x, z3v.y), W0Cv[6], aa);
    ab = pkfma(mk2(z3v.z, z3v.w), W0Cv[7], ab);
    aa = pkfma(mk2(u0v.x, u0v.y), W0Cv[8], aa);
    ab = pkfma(mk2(u0v.z, u0v.w), W0Cv[9], ab);
    aa = pkfma(mk2(u1v.x, u1v.y), W0Cv[10], aa);
    ab = pkfma(mk2(u1v.z, u1v.w), W0Cv[11], ab);
    aaO = aa; abO = ab;
  };
  auto rc1_eval = [&]() -> float {
    float p0 = pdot16(&hR3[0][kbase], W1Cv);
    float o0 = p0 + xchg(p0) + b1CK;
    return rlane(halves_total(tanh_pre(o0) * w2C02), 31) + b2Cs;
  };

  // RK stage split: layer-0 hidden (pre-broadcast) / finish after broadcast.
  auto net_pre = [&](float sxv, float syv) -> float {
    float sv = hi ? syv : sxv;
    return tanh_pre(fmaf(sv, w0K, b0K));
  };
  auto net_post = [&](float sxv, float syv, float rc_m05, float CafF,
                      float& kx, float& ky) {
    float a = dot32(&h12[hi][0], W1v, b1K);
    float v = halves_total(tanh_pre(a) * w2sc);
    float ra = rlane(v, 31) + b2sA;       // r1 (uniform)
    float rb = rlane(v, 63) + b2sB;       // r2 (uniform)
    float dCa = fmaf(-0.03f, sxv, CafF) - ra;
    float dCb = fmaf(-0.02f, syv, fmaf(-3.0f, rb, ra) + rc_m05);
    kx = dCa * (1.0f / 0.3f);
    ky = dCb * (1.0f / 0.2f);
  };

  // ---- prologue: pipeline state for t=0 ----
  v2f aa4, ab4;            // carried z4-prefix accumulators (high half)
  float Az;                // carried A(z_t) (low half)
  r3_l0(aa4, ab4);
  {
    v2f s = aa4 + ab4;
    Az = s.x + s.y;
    float h0 = tanh_pre(Az);
    CFENCE();
    if (!hi) hR3[0][j] = h0;
    CFENCE();
  }
  float rc1 = rc1_eval();

  float u = useq[b * TT];

  for (int t = 0; t < TT; ++t) {
    int tn = (t < TT - 1) ? (t + 1) : t;
    float u_nxt = useq[b * TT + tn];   // prefetch, consumed next iter
    float CafF = fmaf(u, 0.05f, 0.05f);

    if (lane == 0) out[b * TT + t] = make_float2(x0, x1);

    // R0: complete z4 eval (1 pkfma) + z23 via layer-0 linearity; stage-1 h.
    ab4 = pkfma(mk2(x0, x1), WXv, ab4);
    v2f s4v = aa4 + ab4;
    float A4 = s4v.x + s4v.y;                 // A(z4), high lanes
    float Apart = xchg(hi ? A4 : Az);
    float targ = hi ? A4 : (0.5f * (Az + Apart));   // z23 on low half
    float hh = tanh_pre(targ);
    float h1 = net_pre(x0, x1);
    CFENCE();
    // R1: LDS broadcasts
    hR3[1 + hi][j] = hh;        // low -> h(z23), high -> h(z4)
    h12[hi][j] = h1;
    CFENCE();
    // R2: head finish (rc23, rc4) || stage-1 finish || stage-2 layer-0
    float p1 = pdot16(&hR3[1][kbase], W1Cv);
    float p2 = pdot16(&hR3[2][kbase], W1Cv);
    float o1 = p1 + xchg(p1) + b1CK;
    float o2 = p2 + xchg(p2) + b1CK;
    // low half reduces tanh(o1) -> lane31 (rc23); high reduces tanh(o2)
    // -> lane63 (rc4). Per-half DPP trees are independent & symmetric.
    float vv = halves_total(tanh_pre(hi ? o2 : o1) * w2C02);
    float rc23 = rlane(vv, 31) + b2Cs;
    float rc4  = rlane(vv, 63) + b2Cs;
    float kx1, ky1;
    net_post(x0, x1, rc1, CafF, kx1, ky1);
    float sx2 = fmaf(kx1, 0.5f, x0), sy2 = fmaf(ky1, 0.5f, x1);
    float h2 = net_pre(sx2, sy2);
    CFENCE();
    // R3
    h12[hi][j] = h2;
    CFENCE();
    // R4a: stage-2 finish || z-shift (scalar reads then masked write)
    float kx2, ky2;
    net_post(sx2, sy2, rc23, CafF, kx2, ky2);
    {
      // zplus = [zs[2:16], x0, x1, zs[17:24], u]
      int src = (j < 14) ? (j + 2) : ((j < 23) ? (j + 1) : 0);
      float zread = zs[src];
      float znew = (j == 14) ? x0 : ((j == 15) ? x1 : ((j == 23) ? u : zread));
      if ((!hi) && (j < 24)) zs[j] = znew;
    }
    CFENCE();
    // R4b: r3 layer-0 for t+1 (reads shifted zs) || stage-3 layer-0
    r3_l0(aa4, ab4);
    {
      v2f sv2 = aa4 + ab4;
      Az = sv2.x + sv2.y;                  // A(z_{t+1}) on low lanes
      float h0n = tanh_pre(Az);
      if (!hi) hR3[0][j] = h0n;            // h(z_{t+1})
    }
    float sx3 = fmaf(kx2, 0.5f, x0), sy3 = fmaf(ky2, 0.5f, x1);
    float h3 = net_pre(sx3, sy3);
    CFENCE();
    // R5
    h12[hi][j] = h3;
    CFENCE();
    // R6: stage-3 finish || rc1 for t+1 || stage-4 layer-0
    float kx3, ky3;
    net_post(sx3, sy3, rc23, CafF, kx3, ky3);
    rc1 = rc1_eval();
    float sx4 = x0 + kx3, sy4 = x1 + ky3;
    float h4 = net_pre(sx4, sy4);
    CFENCE();
    // R7
    h12[hi][j] = h4;
    CFENCE();
    // R8: stage-4 finish, state update
    float kx4, ky4;
    net_post(sx4, sy4, rc4, CafF, kx4, ky4);
    x0 += (kx1 + 2.0f * (kx2 + kx3) + kx4) * (1.0f / 6.0f);
    x1 += (ky1 + 2.0f * (ky2 + ky3) + ky4) * (1.0f / 6.0f);
    u = u_nxt;
    CFENCE();
  }
}

extern "C" void kernel_launch(void* const* d_in, const int* in_sizes, int n_in,
                              void* d_out, int out_size, void* d_ws, size_t ws_size,
                              hipStream_t stream) {
  const float* p[20];
  for (int i = 0; i < 20; ++i) p[i] = (const float*)d_in[i];
  reac_kernel<<<dim3(4096), dim3(64), 0, stream>>>(
      p[0], p[1], p[2], p[3], p[4], p[5], p[6], p[7], p[8], p[9], p[10],
      p[11], p[12], p[13], p[14], p[15], p[16], p[17], p[18], p[19],
      (float2*)d_out);
}